// Round 8
// baseline (294.211 us; speedup 1.0000x reference)
//
#include <hip/hip_runtime.h>

typedef unsigned short u16;
using bf16x8 = __attribute__((ext_vector_type(8))) short;   // 8 bf16 (4 VGPRs)
using f32x4  = __attribute__((ext_vector_type(4))) float;   // 4 fp32

__device__ __forceinline__ u16 f2b(float f) {
    __bf16 h = (__bf16)f;
    return __builtin_bit_cast(unsigned short, h);
}
__device__ __forceinline__ float b2f(u16 u) {
    return (float)__builtin_bit_cast(__bf16, u);
}
__device__ __forceinline__ void gload16(const u16* g, const u16* l) {
    __builtin_amdgcn_global_load_lds(
        (const __attribute__((address_space(1))) unsigned int*)g,
        (__attribute__((address_space(3))) unsigned int*)l, 16, 0, 0);
}
__device__ __forceinline__ f32x4 mfma16(bf16x8 a, bf16x8 b, f32x4 c) {
    return __builtin_amdgcn_mfma_f32_16x16x32_bf16(a, b, c, 0, 0, 0);
}

// ---------------------------------------------------------------------------
// Fused attention: per block 64 Q-rows, all 2048 KV, out[64][512] f32.
// Grid 256 = 8 batches x 32 Q-tiles; z = lid&7 pins batch to one XCD
// (K 2MB + Vt 2MB = L2). 1024 thr / 16 waves.
// Per KV-chunk (256):
//   S^T[kv][q] = mfma(A=K rows (global), B=Q (LDS)); wave w owns kv strip 16w.
//   P = exp2(S*wk[kv]) -> bf16 -> Ps (LDS, XOR-swizzled); rowsum += bf16-rounded P.
//   O[q][d]  += mfma(A=P (LDS), B=Vt rows (global)); wave w owns d in [32w,32w+32).
// All LDS patterns use the R1-verified conflict-free tiling:
//   row stride 0 mod 128B, byte ^= (row&7)<<4  (8-lane groups tile a 128B stripe).
// No max-subtraction needed (args bounded); denominator = sum of bf16-rounded P
// (matches PV numerator rounding; proven absmax 9.77e-4 in R1-R6).
// ---------------------------------------------------------------------------
__global__ __launch_bounds__(1024, 4)
void attn_fused(const u16* __restrict__ qkv, const u16* __restrict__ Vt,
                const float* __restrict__ wk, float* __restrict__ out)
{
    __shared__ __align__(16) u16 Qs[64 * 512];    // 64KB, row stride 1024B
    __shared__ __align__(16) u16 Ps[64 * 256];    // 32KB, row stride 512B
    __shared__ float rs[64];

    const int tid  = threadIdx.x;
    const int lane = tid & 63;
    const int w    = tid >> 6;                    // wave 0..15
    const int l16  = lane & 15, g = lane >> 4;

    const int lid = blockIdx.x;
    const long z  = lid & 7;                      // batch -> XCD
    const int qt  = lid >> 3;                     // Q-tile 0..31
    const long qrow0 = z * 2048 + (long)qt * 64;

    if (tid < 64) rs[tid] = 0.f;

    // ---- stage Q tile [64][512] via global_load_lds, pre-swizzled source ----
    // chunk ci: q = ci>>6, phys 16B-chunk c = ci&63 holds global chunk c^(q&7).
#pragma unroll
    for (int i = 0; i < 4; ++i) {
        const int ci = i * 1024 + tid;
        const int q = ci >> 6, c = ci & 63;
        const u16* src = qkv + (qrow0 + q) * 1536 + (c ^ (q & 7)) * 8;
        gload16(src, &Qs[(i * 1024 + (tid & ~63)) * 8]);
    }

    f32x4 oacc[4][2] = {};
    float rsum0 = 0.f, rsum1 = 0.f, rsum2 = 0.f, rsum3 = 0.f;

    const u16* Kbase = qkv + z * 2048 * 1536 + 512;           // K cols of qkvC
    const u16* Vbase = Vt + z * 512 * 2048;
    const float* wkb = wk + z * 2048;

    asm volatile("s_waitcnt vmcnt(0)" ::: "memory");
    __syncthreads();

    for (int ch = 0; ch < 8; ++ch) {
        const int c0 = ch * 256;

        // ---------------- S^T phase: this wave's 16 KV rows ----------------
        f32x4 sacc0 = {}, sacc1 = {}, sacc2 = {}, sacc3 = {};
        const u16* Kp = Kbase + (long)(c0 + 16 * w + l16) * 1536 + g * 8;
#pragma unroll
        for (int kf = 0; kf < 16; ++kf) {
            const bf16x8 a = *(const bf16x8*)(Kp + kf * 32);
#pragma unroll
            for (int nf = 0; nf < 4; ++nf) {
                const int q = nf * 16 + l16;
                const int byt = q * 1024 + ((kf * 64 + g * 16) ^ ((q & 7) << 4));
                const bf16x8 b = *(const bf16x8*)((const char*)Qs + byt);
                if (nf == 0) sacc0 = mfma16(a, b, sacc0);
                else if (nf == 1) sacc1 = mfma16(a, b, sacc1);
                else if (nf == 2) sacc2 = mfma16(a, b, sacc2);
                else sacc3 = mfma16(a, b, sacc3);
            }
        }

        // ---------------- P = exp2(S*wk), write to Ps, rowsum ----------------
        const float* wkp = wkb + c0 + 16 * w + g * 4;
        const float wk0 = wkp[0], wk1 = wkp[1], wk2 = wkp[2], wk3 = wkp[3];
#pragma unroll
        for (int nf = 0; nf < 4; ++nf) {
            const f32x4 sv = (nf == 0) ? sacc0 : (nf == 1) ? sacc1 : (nf == 2) ? sacc2 : sacc3;
            const u16 p0 = f2b(exp2f(sv[0] * wk0));
            const u16 p1 = f2b(exp2f(sv[1] * wk1));
            const u16 p2 = f2b(exp2f(sv[2] * wk2));
            const u16 p3 = f2b(exp2f(sv[3] * wk3));
            const float part = b2f(p0) + b2f(p1) + b2f(p2) + b2f(p3);
            if (nf == 0) rsum0 += part;
            else if (nf == 1) rsum1 += part;
            else if (nf == 2) rsum2 += part;
            else rsum3 += part;
            const int q = nf * 16 + l16;
            const int byt = q * 512 + ((32 * w + 8 * g) ^ ((q & 7) << 4));
            uint2 pk;
            pk.x = (unsigned)p0 | ((unsigned)p1 << 16);
            pk.y = (unsigned)p2 | ((unsigned)p3 << 16);
            *(uint2*)((char*)Ps + byt) = pk;
        }
        __syncthreads();                          // Ps visible

        // ---------------- PV phase: this wave's 32 d-cols ----------------
        const u16* Vp = Vbase + (long)(w * 32 + l16) * 2048 + c0 + g * 8;
#pragma unroll
        for (int kf = 0; kf < 8; ++kf) {
            bf16x8 pa0, pa1, pa2, pa3;
            {
                const int q0 = l16;
                pa0 = *(const bf16x8*)((const char*)Ps + q0 * 512 + ((kf * 64 + g * 16) ^ ((q0 & 7) << 4)));
                const int q1 = 16 + l16;
                pa1 = *(const bf16x8*)((const char*)Ps + q1 * 512 + ((kf * 64 + g * 16) ^ ((q1 & 7) << 4)));
                const int q2 = 32 + l16;
                pa2 = *(const bf16x8*)((const char*)Ps + q2 * 512 + ((kf * 64 + g * 16) ^ ((q2 & 7) << 4)));
                const int q3 = 48 + l16;
                pa3 = *(const bf16x8*)((const char*)Ps + q3 * 512 + ((kf * 64 + g * 16) ^ ((q3 & 7) << 4)));
            }
#pragma unroll
            for (int nf = 0; nf < 2; ++nf) {
                const bf16x8 b = *(const bf16x8*)(Vp + nf * 16 * 2048 + kf * 32);
                oacc[0][nf] = mfma16(pa0, b, oacc[0][nf]);
                oacc[1][nf] = mfma16(pa1, b, oacc[1][nf]);
                oacc[2][nf] = mfma16(pa2, b, oacc[2][nf]);
                oacc[3][nf] = mfma16(pa3, b, oacc[3][nf]);
            }
        }
        __syncthreads();                          // Ps free for next chunk
    }

    // ---- rowsum: reduce over g (lanes ^16,^32), then over 16 waves via LDS ----
    {
        float v0 = rsum0, v1 = rsum1, v2 = rsum2, v3 = rsum3;
        v0 += __shfl_xor(v0, 16); v0 += __shfl_xor(v0, 32);
        v1 += __shfl_xor(v1, 16); v1 += __shfl_xor(v1, 32);
        v2 += __shfl_xor(v2, 16); v2 += __shfl_xor(v2, 32);
        v3 += __shfl_xor(v3, 16); v3 += __shfl_xor(v3, 32);
        if (g == 0) {
            atomicAdd(&rs[l16], v0);
            atomicAdd(&rs[16 + l16], v1);
            atomicAdd(&rs[32 + l16], v2);
            atomicAdd(&rs[48 + l16], v3);
        }
    }
    __syncthreads();

    // ---- epilogue: out[q][d] = O / rowsum[q] ----
#pragma unroll
    for (int qf = 0; qf < 4; ++qf)
#pragma unroll
        for (int r = 0; r < 4; ++r) {
            const int row = qf * 16 + g * 4 + r;
            const float inv = 1.0f / rs[row];
#pragma unroll
            for (int nf = 0; nf < 2; ++nf)
                out[(qrow0 + row) * 512 + w * 32 + nf * 16 + l16] = oacc[qf][nf][r] * inv;
        }
}

// ---------------------------------------------------------------------------
// QKV projection GEMM — R5-exact (proven: absmax-stable, 0 bank conflicts).
// C = A * B^T, A[M][512], B[1536][512], C_bf16 = acc + bias[col]. BM=256, BN=128.
// ---------------------------------------------------------------------------
__global__ __launch_bounds__(512, 2)
void proj_gemm(const u16* __restrict__ A, const u16* __restrict__ B,
               u16* __restrict__ C, const float* __restrict__ bias,
               int K, int lda, int ldb, int ldc)
{
    constexpr int BROUND = 2;
    __shared__ __align__(16) u16 sA[2][256 * 64];
    __shared__ __align__(16) u16 sB[2][128 * 64];

    const int tid  = threadIdx.x;
    const int lane = tid & 63;
    const int wave = tid >> 6;
    const int wm = wave >> 2, wn = wave & 3;
    const int l16 = lane & 15, qld = lane >> 4;

    const int gx = gridDim.x, gy = gridDim.y;
    const int nxy = gx * gy;
    int li = blockIdx.y * gx + blockIdx.x;
    li = (li & 7) * (nxy >> 3) + (li >> 3);
    const int bx = li % gx, by = li / gx;
    const int bn0 = bx * 128, bm0 = by * 256;

    const u16* Ab = A + (long)bm0 * lda;
    const u16* Bb = B + (long)bn0 * ldb;

    const u16* srcA[4];
    const u16* srcB[BROUND];
#pragma unroll
    for (int i = 0; i < 4; ++i) {
        const int ci = i * 512 + tid, row = ci >> 3, c = ci & 7;
        srcA[i] = Ab + (long)row * lda + (c ^ (row & 7)) * 8;
    }
#pragma unroll
    for (int i = 0; i < BROUND; ++i) {
        const int ci = i * 512 + tid, row = ci >> 3, c = ci & 7;
        srcB[i] = Bb + (long)row * ldb + (c ^ (row & 7)) * 8;
    }
    const int wch = (tid & ~63) * 8;

#define STAGE_A2(sl, kc, i0) do { \
    gload16(srcA[i0] + (kc),     &sA[sl][(i0) * 4096 + wch]); \
    gload16(srcA[i0 + 1] + (kc), &sA[sl][(i0 + 1) * 4096 + wch]); } while (0)
#define STAGE_B(sl, kc) do { \
    _Pragma("unroll") \
    for (int i = 0; i < BROUND; ++i) \
        gload16(srcB[i] + (kc), &sB[sl][i * 4096 + wch]); } while (0)

    f32x4 acc[8][2] = {};
    const int NT = K >> 6;

    auto rdA = [&](int s, int mf, int kh) -> bf16x8 {
        const int row = wm * 128 + mf * 16 + l16;
        int byte_off = row * 128 + (kh * 32 + qld * 8) * 2;
        byte_off ^= (row & 7) << 4;
        return *(const bf16x8*)((const char*)&sA[s][0] + byte_off);
    };
    auto rdB = [&](int s, int n, int kh) -> bf16x8 {
        const int row = wn * 32 + n * 16 + l16;
        int byte_off = row * 128 + (kh * 32 + qld * 8) * 2;
        byte_off ^= (row & 7) << 4;
        return *(const bf16x8*)((const char*)&sB[s][0] + byte_off);
    };

#define MFMA_HALF(base) do { \
    __builtin_amdgcn_s_setprio(1); \
    _Pragma("unroll") \
    for (int j = 0; j < 4; ++j) \
        _Pragma("unroll") \
        for (int n = 0; n < 2; ++n) \
            acc[(base) + j][n] = mfma16(afr[j], bfr[n], acc[(base) + j][n]); \
    __builtin_amdgcn_s_setprio(0); } while (0)

#define BAR()   asm volatile("s_barrier" ::: "memory")
#define LGKM0() do { asm volatile("s_waitcnt lgkmcnt(0)" ::: "memory"); \
                     __builtin_amdgcn_sched_barrier(0); } while (0)

    STAGE_A2(0, 0, 0); STAGE_A2(0, 0, 2);
    STAGE_B(0, 0);
    STAGE_B(1, 64);
    asm volatile("s_waitcnt vmcnt(%0)" :: "i"(BROUND) : "memory");
    __builtin_amdgcn_sched_barrier(0);
    BAR();

    for (int t = 0; t < NT; ++t) {
        const int s = t & 1, s1 = s ^ 1;
        bf16x8 afr[4], bfr[2];

#pragma unroll
        for (int j = 0; j < 4; ++j) afr[j] = rdA(s, j, 0);
#pragma unroll
        for (int n = 0; n < 2; ++n) bfr[n] = rdB(s, n, 0);
        if (t + 1 < NT) STAGE_A2(s1, (t + 1) * 64, 0);
        BAR(); LGKM0();
        MFMA_HALF(0);
        BAR();

#pragma unroll
        for (int j = 0; j < 4; ++j) afr[j] = rdA(s, 4 + j, 0);
        if (t + 1 < NT) STAGE_A2(s1, (t + 1) * 64, 2);
        BAR(); LGKM0();
        MFMA_HALF(4);
        BAR();

#pragma unroll
        for (int j = 0; j < 4; ++j) afr[j] = rdA(s, j, 1);
#pragma unroll
        for (int n = 0; n < 2; ++n) bfr[n] = rdB(s, n, 1);
        BAR(); LGKM0();
        MFMA_HALF(0);
        BAR();

#pragma unroll
        for (int j = 0; j < 4; ++j) afr[j] = rdA(s, 4 + j, 1);
        if (t + 2 < NT) STAGE_B(s, (t + 2) * 64);
        BAR(); LGKM0();
        MFMA_HALF(4);
        if (t + 2 < NT) asm volatile("s_waitcnt vmcnt(%0)" :: "i"(BROUND) : "memory");
        else            asm volatile("s_waitcnt vmcnt(0)" ::: "memory");
        __builtin_amdgcn_sched_barrier(0);
        BAR();
    }
#undef STAGE_A2
#undef STAGE_B
#undef MFMA_HALF
#undef BAR
#undef LGKM0

    const int rg = lane >> 4;
    const int orow0 = bm0 + wm * 128;
    const int ocol0 = bn0 + wn * 32;

    float bv[2];
#pragma unroll
    for (int n = 0; n < 2; ++n) bv[n] = bias[ocol0 + n * 16 + l16];
#pragma unroll
    for (int mf = 0; mf < 8; ++mf)
#pragma unroll
        for (int n = 0; n < 2; ++n) {
            const int col = ocol0 + n * 16 + l16;
#pragma unroll
            for (int r = 0; r < 4; ++r) {
                const int row = orow0 + mf * 16 + rg * 4 + r;
                C[(long)row * ldc + col] = f2b(acc[mf][n][r] + bv[n]);
            }
        }
}

__global__ void cvt_bf16(const float* __restrict__ in, u16* __restrict__ out, int n4) {
    const int i = blockIdx.x * 256 + threadIdx.x;
    if (i >= n4) return;
    const float4 f = ((const float4*)in)[i];
    ushort4 o;
    o.x = f2b(f.x); o.y = f2b(f.y); o.z = f2b(f.z); o.w = f2b(f.w);
    ((ushort4*)out)[i] = o;
}

__global__ void wk_kernel(const float* __restrict__ eig, float* __restrict__ wk, int n) {
    const int i = blockIdx.x * 256 + threadIdx.x;
    if (i >= n) return;
    const float s = 1.0f / (1.0f + expf(-eig[i]));
    wk[i] = s * (float)(1.4426950408889634 / 22.627416997969522);  // log2(e)/sqrt(512)
}

// V slice of qkvC [16384][1536] (cols 1024..1535) -> Vt [8][512][2048] bf16
__global__ __launch_bounds__(256)
void transpose_v(const u16* __restrict__ Vq, u16* __restrict__ Vt) {
    __shared__ u16 t[64][65];
    const int tid = threadIdx.x;
    const int d0  = blockIdx.x * 64;
    const int bs0 = blockIdx.y * 64;
#pragma unroll
    for (int i = 0; i < 16; ++i) {
        const int idx = i * 256 + tid;
        const int r = idx >> 6, c = idx & 63;
        t[r][c] = Vq[(long)(bs0 + r) * 1536 + d0 + c];
    }
    __syncthreads();
    const long b = bs0 >> 11;
    const int s0 = bs0 & 2047;
#pragma unroll
    for (int i = 0; i < 16; ++i) {
        const int idx = i * 256 + tid;
        const int dch = idx >> 6, ss = idx & 63;
        Vt[(b * 512 + d0 + dch) * 2048 + s0 + ss] = t[ss][dch];
    }
}

extern "C" void kernel_launch(void* const* d_in, const int* in_sizes, int n_in,
                              void* d_out, int out_size, void* d_ws, size_t ws_size,
                              hipStream_t stream) {
    const float* x  = (const float*)d_in[0];
    const float* ev = (const float*)d_in[1];
    const float* Wq = (const float*)d_in[2];
    const float* bq = (const float*)d_in[3];
    const float* Wk = (const float*)d_in[4];
    const float* bk = (const float*)d_in[5];
    const float* Wv = (const float*)d_in[6];
    const float* bv = (const float*)d_in[7];
    float* out = (float*)d_out;

    char* ws = (char*)d_ws;
    u16*   xb     = (u16*)(ws);                      // 16 MB  x bf16 [16384][512]
    u16*   qkvC   = (u16*)(ws + (16ul << 20));       // 48 MB  [16384][1536] = Q|K|V
    u16*   Vt     = (u16*)(ws + (64ul << 20));       // 16 MB  V^T bf16 [8][512][2048]
    u16*   Wb     = (u16*)(ws + (80ul << 20));       // 1.5 MB Wq|Wk|Wv bf16 [1536][512]
    float* biasb  = (float*)(ws + (82ul << 20));     // 6 KB   concat bias [1536]
    float* wk     = (float*)(ws + (83ul << 20));     // 64 KB

    cvt_bf16<<<dim3(8192), dim3(256), 0, stream>>>(x, xb, 2097152);
    cvt_bf16<<<dim3(256),  dim3(256), 0, stream>>>(Wq, Wb,          65536);
    cvt_bf16<<<dim3(256),  dim3(256), 0, stream>>>(Wk, Wb + 262144, 65536);
    cvt_bf16<<<dim3(256),  dim3(256), 0, stream>>>(Wv, Wb + 524288, 65536);
    hipMemcpyAsync(biasb,        bq, 512 * 4, hipMemcpyDeviceToDevice, stream);
    hipMemcpyAsync(biasb + 512,  bk, 512 * 4, hipMemcpyDeviceToDevice, stream);
    hipMemcpyAsync(biasb + 1024, bv, 512 * 4, hipMemcpyDeviceToDevice, stream);
    wk_kernel<<<dim3(64), dim3(256), 0, stream>>>(ev, wk, 16384);

    // QKV projection: M=16384, N=1536 (concat), K=512
    proj_gemm<<<dim3(12, 64), dim3(512), 0, stream>>>(
        xb, Wb, qkvC, biasb, 512, 512, 512, 1536);

    transpose_v<<<dim3(8, 256), dim3(256), 0, stream>>>(qkvC + 1024, Vt);

    // fused scores+softmax+PV: 256 blocks (8 batches x 32 Q-tiles)
    attn_fused<<<dim3(256), dim3(1024), 0, stream>>>(qkvC, Vt, wk, out);
}